// Round 1
// baseline (15475.711 us; speedup 1.0000x reference)
//
#include <hip/hip_runtime.h>
#include <math.h>

// Problem constants
#define NS 256        // batch N
#define CC 22         // channels c
#define DD 64         // matrix dim d
#define NIN 32        // c + 10
#define NPOS 4096     // d*d spatial positions
#define NMAT (NS*CC)  // 5632 matrices
#define PAD 65        // LDS row pad: bank = (65*r + c)%32 varies with r
#define NSWEEP 10     // Jacobi sweeps (63 rounds each)

__device__ __forceinline__ int sub63(int v){ return (v >= 63) ? v - 63 : v; }

// ---------------------------------------------------------------- embedding MLP
__global__ void k_embed(const float* __restrict__ we1, const float* __restrict__ be1,
                        const float* __restrict__ we2, const float* __restrict__ be2,
                        const float* __restrict__ we3, const float* __restrict__ be3,
                        const float* __restrict__ lng, const float* __restrict__ lnb,
                        const int* __restrict__ Mp, float* __restrict__ em3){
  __shared__ float em[10], emln[10], em2[100];
  int tid = threadIdx.x;
  if (tid == 0){
    float md0 = (float)Mp[0] / 500.0f;
    float md1 = 64.0f / 100.0f;
    float mu = 0.f;
    for (int j=0;j<10;++j){ em[j] = md0*we1[j] + md1*we1[10+j] + be1[j]; mu += em[j]; }
    mu *= 0.1f;
    float var = 0.f;
    for (int j=0;j<10;++j){ float d = em[j]-mu; var += d*d; }
    var *= 0.1f;
    float rs = 1.0f/sqrtf(var + 1e-3f);
    for (int j=0;j<10;++j) emln[j] = (em[j]-mu)*rs*lng[j] + lnb[j];
  }
  __syncthreads();
  if (tid < 100){
    float s = be2[tid];
    for (int j=0;j<10;++j) s = fmaf(emln[j], we2[j*100+tid], s);
    em2[tid] = fmaxf(s, 0.f);
  }
  __syncthreads();
  if (tid < 10){
    float s = em[tid] + be3[tid];
    for (int k=0;k<100;++k) s = fmaf(em2[k], we3[k*10+tid], s);
    em3[tid] = s;
  }
}

// ---------------------------------------------------------------- batched Jacobi eigensolver
// one 64x64 symmetric matrix per block (256 threads). A <- J^T A J with 32
// disjoint rotations per round, circle-method tournament pairing (closed form).
__global__ __launch_bounds__(256) void k_eigen(const float* __restrict__ x,
                                               float* __restrict__ logT){
  __shared__ float A[64*PAD];
  __shared__ float V[64*PAD];
  __shared__ float csh[64];
  __shared__ float gv[64];
  const int b = blockIdx.x;
  const int tid = threadIdx.x;
  const float* mat = x + (size_t)b*NPOS;
  // load + symmetrize, V = I
  for (int idx=tid; idx<NPOS; idx+=256){
    int i = idx>>6, j = idx&63;
    A[i*PAD+j] = 0.5f*(mat[idx] + mat[(j<<6)+i]);
    V[i*PAD+j] = (i==j) ? 1.0f : 0.0f;
  }
  __syncthreads();
  for (int sw=0; sw<NSWEEP; ++sw){
    for (int r=0; r<63; ++r){
      // ---- angles for 32 disjoint pairs
      if (tid < 32){
        int i = tid;
        int p = (i==0) ? 0 : (1 + sub63(i-1+r));
        int q = 1 + sub63(62-i+r);
        if (p > q){ int t=p; p=q; q=t; }
        float app = A[p*PAD+p], aqq = A[q*PAD+q], apq = A[p*PAD+q];
        float c = 1.0f, s = 0.0f;
        if (fabsf(apq) > 1e-12f){
          float tau = (aqq-app)/(2.0f*apq);
          float t = copysignf(1.0f, tau)/(fabsf(tau)+sqrtf(1.0f+tau*tau));
          c = 1.0f/sqrtf(1.0f+t*t);
          s = t*c;
        }
        csh[2*i] = c; csh[2*i+1] = s;
      }
      __syncthreads();
      // ---- row phase: A <- J^T A   (wave w handles pairs w, w+4, ...)
      {
        const int w = tid>>6, lane = tid&63;
        for (int i=w; i<32; i+=4){
          int p = (i==0) ? 0 : (1 + sub63(i-1+r));
          int q = 1 + sub63(62-i+r);
          if (p > q){ int t=p; p=q; q=t; }
          float c = csh[2*i], s = csh[2*i+1];
          float ap = A[p*PAD+lane], aq = A[q*PAD+lane];
          A[p*PAD+lane] = c*ap - s*aq;
          A[q*PAD+lane] = s*ap + c*aq;
        }
      }
      __syncthreads();
      // ---- column phase: A <- A J, and V <- V J
      {
        const int w = tid>>6, lane = tid&63;
        for (int i=w; i<32; i+=4){
          int p = (i==0) ? 0 : (1 + sub63(i-1+r));
          int q = 1 + sub63(62-i+r);
          if (p > q){ int t=p; p=q; q=t; }
          float c = csh[2*i], s = csh[2*i+1];
          float ap = A[lane*PAD+p], aq = A[lane*PAD+q];
          A[lane*PAD+p] = c*ap - s*aq;
          A[lane*PAD+q] = s*ap + c*aq;
          float vp = V[lane*PAD+p], vq = V[lane*PAD+q];
          V[lane*PAD+p] = c*vp - s*vq;
          V[lane*PAD+q] = s*vp + c*vq;
        }
      }
      __syncthreads();
    }
  }
  // eigenvalues on diagonal -> g = log(max(lam, 1e-4))
  if (tid < 64) gv[tid] = logf(fmaxf(A[tid*PAD+tid], 1e-4f));
  __syncthreads();
  // W = diag-scaled V (reuse A):  A[k][j] = g[j]*V[k][j]
  for (int idx=tid; idx<NPOS; idx+=256){
    int k = idx>>6, j = idx&63;
    A[k*PAD+j] = gv[j]*V[k*PAD+j];
  }
  __syncthreads();
  // L[i][k] = sum_j V[i][j] * g[j] * V[k][j]
  float* outp = logT + (size_t)b*NPOS;
  for (int idx=tid; idx<NPOS; idx+=256){
    int i = idx>>6, k = idx&63;
    float sum = 0.0f;
    #pragma unroll 8
    for (int j=0; j<64; ++j) sum = fmaf(V[i*PAD+j], A[k*PAD+j], sum);
    outp[idx] = sum;
  }
}

// ---------------------------------------------------------------- per-(n,ch) stats of eu
__global__ __launch_bounds__(256) void k_stats1(const float* __restrict__ logT,
                                                const float* __restrict__ em3,
                                                float* __restrict__ stats1){
  const int n = blockIdx.x, ch = blockIdx.y;
  const int tid = threadIdx.x;
  if (ch >= 22){
    // embedding channels are spatially constant: mean = value, std = 0 -> rstd = 1/1e-3
    if (tid == 0){
      stats1[(n*32+ch)*2+0] = em3[ch-22];
      stats1[(n*32+ch)*2+1] = 1000.0f;
    }
    return;
  }
  const float* p = logT + ((size_t)(n*CC+ch))*NPOS;
  float s = 0.f, s2 = 0.f;
  for (int idx=tid; idx<NPOS; idx+=256){ float v = p[idx]; s += v; s2 = fmaf(v,v,s2); }
  __shared__ float red[4][2];
  for (int off=32; off; off>>=1){ s += __shfl_down(s,off,64); s2 += __shfl_down(s2,off,64); }
  const int w = tid>>6, lane = tid&63;
  if (lane == 0){ red[w][0] = s; red[w][1] = s2; }
  __syncthreads();
  if (tid == 0){
    s  = red[0][0]+red[1][0]+red[2][0]+red[3][0];
    s2 = red[0][1]+red[1][1]+red[2][1]+red[3][1];
    float mean = s*(1.0f/4096.0f);
    float var  = s2*(1.0f/4096.0f) - mean*mean;
    float sd   = sqrtf(fmaxf(var, 0.f));
    stats1[(n*32+ch)*2+0] = mean;
    stats1[(n*32+ch)*2+1] = 1.0f/fmaxf(sd, 1e-3f);
  }
}

// ---------------------------------------------------------------- pass 1: h2 stats
__global__ __launch_bounds__(256) void k_pass1(const float* __restrict__ logT,
    const float* __restrict__ em3, const float* __restrict__ stats1,
    const float* __restrict__ w2, const float* __restrict__ b2,
    const float* __restrict__ w3, const float* __restrict__ b3,
    float* __restrict__ s2raw){
  const int n = blockIdx.x;
  const int tid = threadIdx.x;
  const int pp = (blockIdx.y<<8) + tid;
  __shared__ float w2s[1024], w3s[1024];
  __shared__ float b2s[32], b3s[32], ms[32], rs[32], e3[10];
  __shared__ float redp[4][64];
  for (int i=tid;i<1024;i+=256){ w2s[i]=w2[i]; w3s[i]=w3[i]; }
  if (tid<32){ b2s[tid]=b2[tid]; b3s[tid]=b3[tid];
    ms[tid]=stats1[(n*32+tid)*2]; rs[tid]=stats1[(n*32+tid)*2+1]; }
  if (tid<10) e3[tid]=em3[tid];
  __syncthreads();
  float eu[32], t[32];
  const float* base = logT + (size_t)n*CC*NPOS + pp;
  #pragma unroll
  for (int c=0;c<22;++c) eu[c] = base[c*NPOS];
  #pragma unroll
  for (int c=0;c<10;++c) eu[22+c] = e3[c];
  #pragma unroll
  for (int k=0;k<32;++k) t[k] = b2s[k];
  #pragma unroll
  for (int j=0;j<32;++j){
    float nj = (eu[j]-ms[j])*rs[j];
    #pragma unroll
    for (int k=0;k<32;++k) t[k] = fmaf(nj, w2s[j*32+k], t[k]);
  }
  #pragma unroll
  for (int k=0;k<32;++k){ t[k] = fmaxf(t[k], 0.f); eu[k] += b3s[k]; }
  #pragma unroll
  for (int j=0;j<32;++j){
    float tj = t[j];
    #pragma unroll
    for (int k=0;k<32;++k) eu[k] = fmaf(tj, w3s[j*32+k], eu[k]);
  }
  // eu is now h2 at this position; reduce per-channel sum / sumsq
  const int w = tid>>6, lane = tid&63;
  #pragma unroll
  for (int k=0;k<32;++k){
    float v = eu[k], v2 = v*v;
    for (int off=32; off; off>>=1){ v += __shfl_down(v,off,64); v2 += __shfl_down(v2,off,64); }
    if (lane == 0){ redp[w][2*k] = v; redp[w][2*k+1] = v2; }
  }
  __syncthreads();
  if (tid < 64){
    float v = redp[0][tid]+redp[1][tid]+redp[2][tid]+redp[3][tid];
    atomicAdd(&s2raw[(n<<6)+tid], v);
  }
}

// ---------------------------------------------------------------- finalize h2 stats
__global__ void k_fin2(const float* __restrict__ s2raw, float* __restrict__ stats2){
  int i = blockIdx.x*256 + threadIdx.x;
  if (i < NS*32){
    float s = s2raw[2*i], sq = s2raw[2*i+1];
    float mean = s*(1.0f/4096.0f);
    float var  = sq*(1.0f/4096.0f) - mean*mean;
    float sd   = sqrtf(fmaxf(var, 0.f));
    stats2[2*i]   = mean;
    stats2[2*i+1] = 1.0f/fmaxf(sd, 1e-3f);
  }
}

// ---------------------------------------------------------------- pass 2: h3 accumulation
__global__ __launch_bounds__(256) void k_pass2(const float* __restrict__ logT,
    const float* __restrict__ em3, const float* __restrict__ stats1, const float* __restrict__ stats2,
    const float* __restrict__ w2, const float* __restrict__ b2,
    const float* __restrict__ w3, const float* __restrict__ b3,
    const float* __restrict__ w4, const float* __restrict__ b4,
    const float* __restrict__ w5, const float* __restrict__ b5,
    float* __restrict__ cov3){
  const int n = blockIdx.x;
  const int tid = threadIdx.x;
  const int pp = (blockIdx.y<<8) + tid;
  __shared__ float w2s[1024], w3s[1024], w4s[1024], w5s[1024];
  __shared__ float b2s[32], b3s[32], b4s[32], b5s[32];
  __shared__ float m1[32], r1[32], m2[32], r2[32], e3[10];
  __shared__ float redp[4][32];
  for (int i=tid;i<1024;i+=256){ w2s[i]=w2[i]; w3s[i]=w3[i]; w4s[i]=w4[i]; w5s[i]=w5[i]; }
  if (tid<32){ b2s[tid]=b2[tid]; b3s[tid]=b3[tid]; b4s[tid]=b4[tid]; b5s[tid]=b5[tid];
    m1[tid]=stats1[(n*32+tid)*2]; r1[tid]=stats1[(n*32+tid)*2+1];
    m2[tid]=stats2[(n*32+tid)*2]; r2[tid]=stats2[(n*32+tid)*2+1]; }
  if (tid<10) e3[tid]=em3[tid];
  __syncthreads();
  float eu[32], t[32];
  const float* base = logT + (size_t)n*CC*NPOS + pp;
  #pragma unroll
  for (int c=0;c<22;++c) eu[c] = base[c*NPOS];
  #pragma unroll
  for (int c=0;c<10;++c) eu[22+c] = e3[c];
  // --- recompute h2 ---
  #pragma unroll
  for (int k=0;k<32;++k) t[k] = b2s[k];
  #pragma unroll
  for (int j=0;j<32;++j){
    float nj = (eu[j]-m1[j])*r1[j];
    #pragma unroll
    for (int k=0;k<32;++k) t[k] = fmaf(nj, w2s[j*32+k], t[k]);
  }
  #pragma unroll
  for (int k=0;k<32;++k){ t[k] = fmaxf(t[k], 0.f); eu[k] += b3s[k]; }
  #pragma unroll
  for (int j=0;j<32;++j){
    float tj = t[j];
    #pragma unroll
    for (int k=0;k<32;++k) eu[k] = fmaf(tj, w3s[j*32+k], eu[k]);
  }
  // --- second residual block: h3 = h2 + relu(matnorm(h2)@w4+b4)@w5 + b5 ---
  #pragma unroll
  for (int k=0;k<32;++k) t[k] = b4s[k];
  #pragma unroll
  for (int j=0;j<32;++j){
    float nj = (eu[j]-m2[j])*r2[j];
    #pragma unroll
    for (int k=0;k<32;++k) t[k] = fmaf(nj, w4s[j*32+k], t[k]);
  }
  #pragma unroll
  for (int k=0;k<32;++k){ t[k] = fmaxf(t[k], 0.f); eu[k] += b5s[k]; }
  #pragma unroll
  for (int j=0;j<32;++j){
    float tj = t[j];
    #pragma unroll
    for (int k=0;k<32;++k) eu[k] = fmaf(tj, w5s[j*32+k], eu[k]);
  }
  // eu is h3; accumulate per-channel spatial sums
  const int w = tid>>6, lane = tid&63;
  #pragma unroll
  for (int k=0;k<32;++k){
    float v = eu[k];
    for (int off=32; off; off>>=1) v += __shfl_down(v,off,64);
    if (lane == 0) redp[w][k] = v;
  }
  __syncthreads();
  if (tid < 32){
    float v = redp[0][tid]+redp[1][tid]+redp[2][tid]+redp[3][tid];
    atomicAdd(&cov3[(n<<5)+tid], v);
  }
}

// ---------------------------------------------------------------- head: mean -> matmul -> softmax
__global__ void k_out(const float* __restrict__ cov3, const float* __restrict__ w,
                      float* __restrict__ out){
  __shared__ float wsm[224];
  const int tid = threadIdx.x;
  if (tid < 224) wsm[tid] = w[tid];
  __syncthreads();
  const int n = tid;  // 256 threads = 256 samples
  float l[7];
  #pragma unroll
  for (int c=0;c<7;++c) l[c] = 0.f;
  #pragma unroll
  for (int ch=0;ch<32;++ch){
    float v = cov3[(n<<5)+ch]*(1.0f/4096.0f);
    #pragma unroll
    for (int c=0;c<7;++c) l[c] = fmaf(v, wsm[ch*7+c], l[c]);
  }
  float mx = l[0];
  #pragma unroll
  for (int c=1;c<7;++c) mx = fmaxf(mx, l[c]);
  float ssum = 0.f;
  #pragma unroll
  for (int c=0;c<7;++c){ l[c] = expf(l[c]-mx); ssum += l[c]; }
  float inv = 1.0f/ssum;
  #pragma unroll
  for (int c=0;c<7;++c) out[n*7+c] = l[c]*inv;
}

// ----------------------------------------------------------------
extern "C" void kernel_launch(void* const* d_in, const int* in_sizes, int n_in,
                              void* d_out, int out_size, void* d_ws, size_t ws_size,
                              hipStream_t stream){
  const float* x   = (const float*)d_in[0];
  const int*   Mp  = (const int*)  d_in[1];
  const float* w   = (const float*)d_in[2];
  const float* w2  = (const float*)d_in[3];
  const float* b2  = (const float*)d_in[4];
  const float* w3  = (const float*)d_in[5];
  const float* b3  = (const float*)d_in[6];
  const float* w4  = (const float*)d_in[7];
  const float* b4  = (const float*)d_in[8];
  const float* w5  = (const float*)d_in[9];
  const float* b5  = (const float*)d_in[10];
  const float* we1 = (const float*)d_in[11];
  const float* be1 = (const float*)d_in[12];
  const float* we2 = (const float*)d_in[13];
  const float* be2 = (const float*)d_in[14];
  const float* we3 = (const float*)d_in[15];
  const float* be3 = (const float*)d_in[16];
  const float* lng = (const float*)d_in[17];
  const float* lnb = (const float*)d_in[18];

  float* wsf    = (float*)d_ws;
  float* logT   = wsf;                           // [N,22,4096]  92.3 MB
  float* em3    = logT + (size_t)NMAT*NPOS;      // 16
  float* stats1 = em3 + 16;                      // [N,32,2]
  float* s2raw  = stats1 + NS*64;                // [N,32,2] accum (zeroed)
  float* cov3   = s2raw + NS*64;                 // [N,32]   accum (zeroed)
  float* stats2 = cov3 + NS*32;                  // [N,32,2]

  // zero the atomic accumulators (ws is poisoned 0xAA before every launch)
  hipMemsetAsync(s2raw, 0, (size_t)(NS*64 + NS*32)*sizeof(float), stream);

  k_embed <<<1, 128, 0, stream>>>(we1,be1,we2,be2,we3,be3,lng,lnb,Mp,em3);
  k_eigen <<<NMAT, 256, 0, stream>>>(x, logT);
  k_stats1<<<dim3(NS,32), 256, 0, stream>>>(logT, em3, stats1);
  k_pass1 <<<dim3(NS,16), 256, 0, stream>>>(logT, em3, stats1, w2,b2,w3,b3, s2raw);
  k_fin2  <<<(NS*32+255)/256, 256, 0, stream>>>(s2raw, stats2);
  k_pass2 <<<dim3(NS,16), 256, 0, stream>>>(logT, em3, stats1, stats2,
                                            w2,b2,w3,b3,w4,b4,w5,b5, cov3);
  k_out   <<<1, 256, 0, stream>>>(cov3, w, (float*)d_out);
}

// Round 2
// 11592.686 us; speedup vs baseline: 1.3350x; 1.3350x over previous
//
#include <hip/hip_runtime.h>
#include <math.h>

// Problem constants
#define NS 256        // batch N
#define CC 22         // channels c
#define DD 64         // matrix dim d
#define NPOS 4096     // d*d spatial positions
#define NMAT (NS*CC)  // 5632 matrices
#define NSWEEP 10     // one-sided Jacobi sweeps (63 XOR rounds each; late rounds skip)

// ---------------------------------------------------------------- embedding MLP
__global__ void k_embed(const float* __restrict__ we1, const float* __restrict__ be1,
                        const float* __restrict__ we2, const float* __restrict__ be2,
                        const float* __restrict__ we3, const float* __restrict__ be3,
                        const float* __restrict__ lng, const float* __restrict__ lnb,
                        const int* __restrict__ Mp, float* __restrict__ em3){
  __shared__ float em[10], emln[10], em2[100];
  int tid = threadIdx.x;
  if (tid == 0){
    float md0 = (float)Mp[0] / 500.0f;
    float md1 = 64.0f / 100.0f;
    float mu = 0.f;
    for (int j=0;j<10;++j){ em[j] = md0*we1[j] + md1*we1[10+j] + be1[j]; mu += em[j]; }
    mu *= 0.1f;
    float var = 0.f;
    for (int j=0;j<10;++j){ float d = em[j]-mu; var += d*d; }
    var *= 0.1f;
    float rs = 1.0f/sqrtf(var + 1e-3f);
    for (int j=0;j<10;++j) emln[j] = (em[j]-mu)*rs*lng[j] + lnb[j];
  }
  __syncthreads();
  if (tid < 100){
    float s = be2[tid];
    for (int j=0;j<10;++j) s = fmaf(emln[j], we2[j*100+tid], s);
    em2[tid] = fmaxf(s, 0.f);
  }
  __syncthreads();
  if (tid < 10){
    float s = em[tid] + be3[tid];
    for (int k=0;k<100;++k) s = fmaf(em2[k], we3[k*10+tid], s);
    em3[tid] = s;
  }
}

// ---------------------------------------------------------------- one-sided Jacobi, 1 wave/matrix
// Lane j owns column j of W (=A evolving) and V. XOR tournament pairing; partner
// columns via ds_bpermute. All register indices static; no LDS, no barriers.
__global__ __launch_bounds__(256) void k_jacobi(const float* __restrict__ x,
                                                float* __restrict__ Vg,
                                                float* __restrict__ gw){
  const int lane = threadIdx.x & 63;
  const int b = blockIdx.x*4 + (threadIdx.x>>6);
  const float* mat = x + (size_t)b*NPOS;
  float a[64], v[64];
  #pragma unroll
  for (int i=0;i<64;++i){
    a[i] = 0.5f*(mat[(i<<6)+lane] + mat[(lane<<6)+i]);
    v[i] = (i==lane) ? 1.0f : 0.0f;
  }
  float own = 0.f;
  #pragma unroll 1
  for (int sw=0; sw<NSWEEP; ++sw){
    // exact norm refresh once per sweep (kills incremental drift)
    own = 0.f;
    #pragma unroll
    for (int i=0;i<64;++i) own = fmaf(a[i], a[i], own);
    #pragma unroll 1
    for (int m=1; m<64; ++m){
      const int pij = ((lane ^ m) << 2);   // bpermute byte index, hoisted
      // Gram cross-dot with partner column (symmetric in the pair)
      float d = 0.f;
      #pragma unroll
      for (int i=0;i<64;++i){
        float t = __int_as_float(__builtin_amdgcn_ds_bpermute(pij, __float_as_int(a[i])));
        d = fmaf(a[i], t, d);
      }
      float oth = __int_as_float(__builtin_amdgcn_ds_bpermute(pij, __float_as_int(own)));
      bool rot = (d*d > 1e-14f*own*oth);
      if (__any(rot)){
        // per-lane angle: tau = (oth-own)/(2d) gives s with correct sign on both
        // sides of the pair automatically (lane q sees -tau -> -s).
        float tau = (oth - own)/(2.0f*d);
        float tt  = copysignf(1.0f, tau)/(fabsf(tau) + sqrtf(fmaf(tau,tau,1.0f)));
        float c   = 1.0f/sqrtf(fmaf(tt,tt,1.0f));
        float s   = tt*c;
        if (!rot){ c = 1.0f; s = 0.0f; tt = 0.0f; }  // also kills 0/0 NaN
        own = fmaf(-tt, d, own);                      // ||w||^2 update (Golub-Van Loan)
        float ns = -s;
        #pragma unroll
        for (int i=0;i<64;++i){
          float t = __int_as_float(__builtin_amdgcn_ds_bpermute(pij, __float_as_int(a[i])));
          a[i] = fmaf(ns, t, c*a[i]);
        }
        #pragma unroll
        for (int i=0;i<64;++i){
          float t = __int_as_float(__builtin_amdgcn_ds_bpermute(pij, __float_as_int(v[i])));
          v[i] = fmaf(ns, t, c*v[i]);
        }
      }
    }
  }
  // sigma = ||w||, eigenvalue sign from w.v  (w = sigma*u, v unit: A = Q L Q^T)
  float nrm = 0.f, dsg = 0.f;
  #pragma unroll
  for (int i=0;i<64;++i){ nrm = fmaf(a[i],a[i],nrm); dsg = fmaf(a[i],v[i],dsg); }
  float lam = copysignf(sqrtf(nrm), dsg);
  float g = logf(fmaxf(lam, 1e-4f));
  float* vp = Vg + (size_t)b*NPOS;
  #pragma unroll
  for (int i=0;i<64;++i) vp[(i<<6)+lane] = v[i];   // V row-major, coalesced
  gw[(b<<6)+lane] = g;
}

// ---------------------------------------------------------------- L = V diag(g) V^T (in place over V)
#define VP 68   // stride for b128 broadcast rows
#define WP 65   // stride for lane-varying b32 reads (2-way, free)
__global__ __launch_bounds__(256) void k_logm(float* __restrict__ VL,
                                              const float* __restrict__ gw){
  __shared__ float Vr[64*VP];
  __shared__ float Wr[64*WP];
  const int b = blockIdx.x, tid = threadIdx.x;
  float* base = VL + (size_t)b*NPOS;
  const float* gp = gw + (b<<6);
  for (int idx=tid; idx<NPOS; idx+=256){
    int i = idx>>6, j = idx&63;
    float vv = base[idx];
    Vr[i*VP+j] = vv;
    Wr[i*WP+j] = gp[j]*vv;
  }
  __syncthreads();
  for (int idx=tid; idx<NPOS; idx+=256){
    int i = idx>>6, k = idx&63;            // i wave-uniform, k = lane
    const float4* vrow = (const float4*)&Vr[i*VP];
    const float*  wrow = &Wr[k*WP];
    float4 acc = {0.f,0.f,0.f,0.f};
    #pragma unroll
    for (int j=0;j<16;++j){
      float4 a4 = vrow[j];                 // broadcast (same addr all lanes)
      acc.x = fmaf(a4.x, wrow[4*j+0], acc.x);
      acc.y = fmaf(a4.y, wrow[4*j+1], acc.y);
      acc.z = fmaf(a4.z, wrow[4*j+2], acc.z);
      acc.w = fmaf(a4.w, wrow[4*j+3], acc.w);
    }
    base[idx] = (acc.x+acc.y)+(acc.z+acc.w);  // overwrite V with L
  }
}

// ---------------------------------------------------------------- per-(n,ch) stats of eu
__global__ __launch_bounds__(256) void k_stats1(const float* __restrict__ logT,
                                                const float* __restrict__ em3,
                                                float* __restrict__ stats1){
  const int n = blockIdx.x, ch = blockIdx.y;
  const int tid = threadIdx.x;
  if (ch >= 22){
    if (tid == 0){
      stats1[(n*32+ch)*2+0] = em3[ch-22];
      stats1[(n*32+ch)*2+1] = 1000.0f;
    }
    return;
  }
  const float* p = logT + ((size_t)(n*CC+ch))*NPOS;
  float s = 0.f, s2 = 0.f;
  for (int idx=tid; idx<NPOS; idx+=256){ float v = p[idx]; s += v; s2 = fmaf(v,v,s2); }
  __shared__ float red[4][2];
  for (int off=32; off; off>>=1){ s += __shfl_down(s,off,64); s2 += __shfl_down(s2,off,64); }
  const int w = tid>>6, lane = tid&63;
  if (lane == 0){ red[w][0] = s; red[w][1] = s2; }
  __syncthreads();
  if (tid == 0){
    s  = red[0][0]+red[1][0]+red[2][0]+red[3][0];
    s2 = red[0][1]+red[1][1]+red[2][1]+red[3][1];
    float mean = s*(1.0f/4096.0f);
    float var  = s2*(1.0f/4096.0f) - mean*mean;
    float sd   = sqrtf(fmaxf(var, 0.f));
    stats1[(n*32+ch)*2+0] = mean;
    stats1[(n*32+ch)*2+1] = 1.0f/fmaxf(sd, 1e-3f);
  }
}

// ---------------------------------------------------------------- pass 1: h2 stats
__global__ __launch_bounds__(256) void k_pass1(const float* __restrict__ logT,
    const float* __restrict__ em3, const float* __restrict__ stats1,
    const float* __restrict__ w2, const float* __restrict__ b2,
    const float* __restrict__ w3, const float* __restrict__ b3,
    float* __restrict__ s2raw){
  const int n = blockIdx.x;
  const int tid = threadIdx.x;
  const int pp = (blockIdx.y<<8) + tid;
  __shared__ float w2s[1024], w3s[1024];
  __shared__ float b2s[32], b3s[32], ms[32], rs[32], e3[10];
  __shared__ float redp[4][64];
  for (int i=tid;i<1024;i+=256){ w2s[i]=w2[i]; w3s[i]=w3[i]; }
  if (tid<32){ b2s[tid]=b2[tid]; b3s[tid]=b3[tid];
    ms[tid]=stats1[(n*32+tid)*2]; rs[tid]=stats1[(n*32+tid)*2+1]; }
  if (tid<10) e3[tid]=em3[tid];
  __syncthreads();
  float eu[32], t[32];
  const float* base = logT + (size_t)n*CC*NPOS + pp;
  #pragma unroll
  for (int c=0;c<22;++c) eu[c] = base[c*NPOS];
  #pragma unroll
  for (int c=0;c<10;++c) eu[22+c] = e3[c];
  #pragma unroll
  for (int k=0;k<32;++k) t[k] = b2s[k];
  #pragma unroll
  for (int j=0;j<32;++j){
    float nj = (eu[j]-ms[j])*rs[j];
    #pragma unroll
    for (int k=0;k<32;++k) t[k] = fmaf(nj, w2s[j*32+k], t[k]);
  }
  #pragma unroll
  for (int k=0;k<32;++k){ t[k] = fmaxf(t[k], 0.f); eu[k] += b3s[k]; }
  #pragma unroll
  for (int j=0;j<32;++j){
    float tj = t[j];
    #pragma unroll
    for (int k=0;k<32;++k) eu[k] = fmaf(tj, w3s[j*32+k], eu[k]);
  }
  const int w = tid>>6, lane = tid&63;
  #pragma unroll
  for (int k=0;k<32;++k){
    float v = eu[k], v2 = v*v;
    for (int off=32; off; off>>=1){ v += __shfl_down(v,off,64); v2 += __shfl_down(v2,off,64); }
    if (lane == 0){ redp[w][2*k] = v; redp[w][2*k+1] = v2; }
  }
  __syncthreads();
  if (tid < 64){
    float v = redp[0][tid]+redp[1][tid]+redp[2][tid]+redp[3][tid];
    atomicAdd(&s2raw[(n<<6)+tid], v);
  }
}

// ---------------------------------------------------------------- finalize h2 stats
__global__ void k_fin2(const float* __restrict__ s2raw, float* __restrict__ stats2){
  int i = blockIdx.x*256 + threadIdx.x;
  if (i < NS*32){
    float s = s2raw[2*i], sq = s2raw[2*i+1];
    float mean = s*(1.0f/4096.0f);
    float var  = sq*(1.0f/4096.0f) - mean*mean;
    float sd   = sqrtf(fmaxf(var, 0.f));
    stats2[2*i]   = mean;
    stats2[2*i+1] = 1.0f/fmaxf(sd, 1e-3f);
  }
}

// ---------------------------------------------------------------- pass 2: h3 accumulation
__global__ __launch_bounds__(256) void k_pass2(const float* __restrict__ logT,
    const float* __restrict__ em3, const float* __restrict__ stats1, const float* __restrict__ stats2,
    const float* __restrict__ w2, const float* __restrict__ b2,
    const float* __restrict__ w3, const float* __restrict__ b3,
    const float* __restrict__ w4, const float* __restrict__ b4,
    const float* __restrict__ w5, const float* __restrict__ b5,
    float* __restrict__ cov3){
  const int n = blockIdx.x;
  const int tid = threadIdx.x;
  const int pp = (blockIdx.y<<8) + tid;
  __shared__ float w2s[1024], w3s[1024], w4s[1024], w5s[1024];
  __shared__ float b2s[32], b3s[32], b4s[32], b5s[32];
  __shared__ float m1[32], r1[32], m2[32], r2[32], e3[10];
  __shared__ float redp[4][32];
  for (int i=tid;i<1024;i+=256){ w2s[i]=w2[i]; w3s[i]=w3[i]; w4s[i]=w4[i]; w5s[i]=w5[i]; }
  if (tid<32){ b2s[tid]=b2[tid]; b3s[tid]=b3[tid]; b4s[tid]=b4[tid]; b5s[tid]=b5[tid];
    m1[tid]=stats1[(n*32+tid)*2]; r1[tid]=stats1[(n*32+tid)*2+1];
    m2[tid]=stats2[(n*32+tid)*2]; r2[tid]=stats2[(n*32+tid)*2+1]; }
  if (tid<10) e3[tid]=em3[tid];
  __syncthreads();
  float eu[32], t[32];
  const float* base = logT + (size_t)n*CC*NPOS + pp;
  #pragma unroll
  for (int c=0;c<22;++c) eu[c] = base[c*NPOS];
  #pragma unroll
  for (int c=0;c<10;++c) eu[22+c] = e3[c];
  #pragma unroll
  for (int k=0;k<32;++k) t[k] = b2s[k];
  #pragma unroll
  for (int j=0;j<32;++j){
    float nj = (eu[j]-m1[j])*r1[j];
    #pragma unroll
    for (int k=0;k<32;++k) t[k] = fmaf(nj, w2s[j*32+k], t[k]);
  }
  #pragma unroll
  for (int k=0;k<32;++k){ t[k] = fmaxf(t[k], 0.f); eu[k] += b3s[k]; }
  #pragma unroll
  for (int j=0;j<32;++j){
    float tj = t[j];
    #pragma unroll
    for (int k=0;k<32;++k) eu[k] = fmaf(tj, w3s[j*32+k], eu[k]);
  }
  #pragma unroll
  for (int k=0;k<32;++k) t[k] = b4s[k];
  #pragma unroll
  for (int j=0;j<32;++j){
    float nj = (eu[j]-m2[j])*r2[j];
    #pragma unroll
    for (int k=0;k<32;++k) t[k] = fmaf(nj, w4s[j*32+k], t[k]);
  }
  #pragma unroll
  for (int k=0;k<32;++k){ t[k] = fmaxf(t[k], 0.f); eu[k] += b5s[k]; }
  #pragma unroll
  for (int j=0;j<32;++j){
    float tj = t[j];
    #pragma unroll
    for (int k=0;k<32;++k) eu[k] = fmaf(tj, w5s[j*32+k], eu[k]);
  }
  const int w = tid>>6, lane = tid&63;
  #pragma unroll
  for (int k=0;k<32;++k){
    float v = eu[k];
    for (int off=32; off; off>>=1) v += __shfl_down(v,off,64);
    if (lane == 0) redp[w][k] = v;
  }
  __syncthreads();
  if (tid < 32){
    float v = redp[0][tid]+redp[1][tid]+redp[2][tid]+redp[3][tid];
    atomicAdd(&cov3[(n<<5)+tid], v);
  }
}

// ---------------------------------------------------------------- head: mean -> matmul -> softmax
__global__ void k_out(const float* __restrict__ cov3, const float* __restrict__ w,
                      float* __restrict__ out){
  __shared__ float wsm[224];
  const int tid = threadIdx.x;
  if (tid < 224) wsm[tid] = w[tid];
  __syncthreads();
  const int n = tid;
  float l[7];
  #pragma unroll
  for (int c=0;c<7;++c) l[c] = 0.f;
  #pragma unroll
  for (int ch=0;ch<32;++ch){
    float v = cov3[(n<<5)+ch]*(1.0f/4096.0f);
    #pragma unroll
    for (int c=0;c<7;++c) l[c] = fmaf(v, wsm[ch*7+c], l[c]);
  }
  float mx = l[0];
  #pragma unroll
  for (int c=1;c<7;++c) mx = fmaxf(mx, l[c]);
  float ssum = 0.f;
  #pragma unroll
  for (int c=0;c<7;++c){ l[c] = expf(l[c]-mx); ssum += l[c]; }
  float inv = 1.0f/ssum;
  #pragma unroll
  for (int c=0;c<7;++c) out[n*7+c] = l[c]*inv;
}

// ----------------------------------------------------------------
extern "C" void kernel_launch(void* const* d_in, const int* in_sizes, int n_in,
                              void* d_out, int out_size, void* d_ws, size_t ws_size,
                              hipStream_t stream){
  const float* x   = (const float*)d_in[0];
  const int*   Mp  = (const int*)  d_in[1];
  const float* w   = (const float*)d_in[2];
  const float* w2  = (const float*)d_in[3];
  const float* b2  = (const float*)d_in[4];
  const float* w3  = (const float*)d_in[5];
  const float* b3  = (const float*)d_in[6];
  const float* w4  = (const float*)d_in[7];
  const float* b4  = (const float*)d_in[8];
  const float* w5  = (const float*)d_in[9];
  const float* b5  = (const float*)d_in[10];
  const float* we1 = (const float*)d_in[11];
  const float* be1 = (const float*)d_in[12];
  const float* we2 = (const float*)d_in[13];
  const float* be2 = (const float*)d_in[14];
  const float* we3 = (const float*)d_in[15];
  const float* be3 = (const float*)d_in[16];
  const float* lng = (const float*)d_in[17];
  const float* lnb = (const float*)d_in[18];

  float* wsf    = (float*)d_ws;
  float* VL     = wsf;                           // [NMAT,4096] V then L in place (92.3 MB)
  float* gw     = VL + (size_t)NMAT*NPOS;        // [NMAT,64]
  float* em3    = gw + (size_t)NMAT*64;          // 16
  float* stats1 = em3 + 16;                      // [N,32,2]
  float* s2raw  = stats1 + NS*64;                // [N,32,2] accum (zeroed)
  float* cov3   = s2raw + NS*64;                 // [N,32]   accum (zeroed)
  float* stats2 = cov3 + NS*32;                  // [N,32,2]

  hipMemsetAsync(s2raw, 0, (size_t)(NS*64 + NS*32)*sizeof(float), stream);

  k_embed <<<1, 128, 0, stream>>>(we1,be1,we2,be2,we3,be3,lng,lnb,Mp,em3);
  k_jacobi<<<NMAT/4, 256, 0, stream>>>(x, VL, gw);
  k_logm  <<<NMAT, 256, 0, stream>>>(VL, gw);
  k_stats1<<<dim3(NS,32), 256, 0, stream>>>(VL, em3, stats1);
  k_pass1 <<<dim3(NS,16), 256, 0, stream>>>(VL, em3, stats1, w2,b2,w3,b3, s2raw);
  k_fin2  <<<(NS*32+255)/256, 256, 0, stream>>>(s2raw, stats2);
  k_pass2 <<<dim3(NS,16), 256, 0, stream>>>(VL, em3, stats1, stats2,
                                            w2,b2,w3,b3,w4,b4,w5,b5, cov3);
  k_out   <<<1, 256, 0, stream>>>(cov3, w, (float*)d_out);
}